// Round 1
// baseline (253.860 us; speedup 1.0000x reference)
//
#include <hip/hip_runtime.h>
#include <hip/hip_bf16.h>

// out[i][d] = params[idx[i]] * xs[i][d];  N=4194304, D=8, V=1048576
// Memory-bound gather-scale. One thread per float4 (2 per row).

__global__ __launch_bounds__(256) void spvar_kernel(
    const float4* __restrict__ xs4,
    const int*    __restrict__ idx,
    const float*  __restrict__ params,
    float4*       __restrict__ out4,
    int n4)   // n4 = N*D/4 = 8388608 (fits int32)
{
    int tid = blockIdx.x * blockDim.x + threadIdx.x;
    if (tid >= n4) return;
    int row = tid >> 1;               // D=8 -> 2 float4 per row
    float p = params[idx[row]];
    float4 x = xs4[tid];
    float4 o;
    o.x = x.x * p;
    o.y = x.y * p;
    o.z = x.z * p;
    o.w = x.w * p;
    out4[tid] = o;
}

extern "C" void kernel_launch(void* const* d_in, const int* in_sizes, int n_in,
                              void* d_out, int out_size, void* d_ws, size_t ws_size,
                              hipStream_t stream) {
    const float* xs     = (const float*)d_in[0];   // [N, 8] f32
    const int*   idx    = (const int*)d_in[1];     // [N] int32 (jax x64 off)
    const float* params = (const float*)d_in[2];   // [V, 1] f32

    const int n4 = out_size / 4;                   // N*D/4
    const int block = 256;
    const int grid = (n4 + block - 1) / block;

    spvar_kernel<<<grid, block, 0, stream>>>(
        (const float4*)xs, idx, params, (float4*)d_out, n4);
}